// Round 15
// baseline (148.332 us; speedup 1.0000x reference)
//
#include <hip/hip_runtime.h>

#define N_ROWS 8192
#define NX     4096
#define DIM    512
#define BT     128          // block tile (rows & cols)
#define NT     64           // N_ROWS / BT tiles per side
#define NTRI   2080         // NT*(NT+1)/2 upper-triangle tiles
#define BK     32           // K elements per stage (64 B per row)
#define NPERS  768          // persistent blocks: exactly 3 per CU
#define CSBASE 640          // colsum duty: blocks 640..767 (2-tile blocks)

typedef __bf16 bf16_t;
typedef bf16_t bf16x8 __attribute__((ext_vector_type(8)));
typedef float  f32x4  __attribute__((ext_vector_type(4)));

#if __has_builtin(__builtin_amdgcn_exp2f)
  #define EXP2F __builtin_amdgcn_exp2f
#else
  #define EXP2F exp2f
#endif

// ws layout (bytes):
//   0       sqrow[8192]  float
//   32768   colsum[512]  float
//   34816   cvals[5]     float   cvals[k] = -log2e/(bw*mult_k)
//   34840   tk1          uint    colsum ticket
//   34844   tk2          uint    final ticket
//   34848   S1acc        double  sum of sqrow
//   34860   flag         uint    cvals-ready flag
//   34944   acc[8*16]    double  8 slots, 128 B apart
//   36864   Zh[8192*512] bf16
//
// NO __threadfence (R7/R8: per-block L2 writeback doubled stage latency
// chip-wide). Ordering = returning atomic -> asm sink -> vmcnt(0) ->
// flag/ticket atomic. STATIC tiles (b, b+768, b+1536) keep T&7 == b&7 ==
// XCD (R12's dynamic queue broke it: FETCH 22->71 MB, 63->119 us).
// R13 lesson: phase-A colsum at prio 0 was STARVED by K-loop setprio(1)
// MFMA clusters -> flag late -> whole machine spun in first epilogue
// (97.9 us, MfmaUtil 14). Fix: phase A at setprio(2) + stages pre-issued.

__device__ __forceinline__ const float* zrow(const float* X, const float* Y, int r) {
    return (r < NX) ? (X + (size_t)r * DIM) : (Y + (size_t)(r - NX) * DIM);
}

__device__ __forceinline__ void gload_lds16(const bf16_t* g, bf16_t* l) {
    __builtin_amdgcn_global_load_lds(
        (__attribute__((address_space(1))) void*)(void*)(g),
        (__attribute__((address_space(3))) void*)(void*)(l), 16, 0, 0);
}

// supertile-blocked triangular decode (8x8-tile supertiles) + XCD spread
__device__ __forceinline__ void decode_tile(int T, int* pti, int* ptj) {
    int q = (T & 7) * (NTRI / 8) + (T >> 3);
    int I = 0, rem = q;
    #pragma unroll
    for (int it = 0; it < 8; ++it) {
        int rowcnt = 36 + (7 - I) * 64;
        if (rem >= rowcnt && I < 7) { rem -= rowcnt; ++I; } else break;
    }
    if (rem < 36) {
        int a = 0;
        #pragma unroll
        for (int it = 0; it < 7; ++it) {
            int nxt = (a + 1) * 8 - (a + 1) * a / 2;
            if (nxt <= rem) ++a; else break;
        }
        int off = a * 8 - a * (a - 1) / 2;
        *pti = I * 8 + a;
        *ptj = I * 8 + a + (rem - off);
    } else {
        int r2 = rem - 36;
        int J = I + 1 + (r2 >> 6);
        int w = r2 & 63;
        *pti = I * 8 + (w >> 3);
        *ptj = J * 8 + (w & 7);
    }
}

// fused: bf16 copy + exact fp32 row norms + zero-init of control state.
__global__ void k_prep(const float* __restrict__ X, const float* __restrict__ Y,
                       bf16_t* __restrict__ Zh, float* __restrict__ sqrow,
                       float* __restrict__ colsum, unsigned* __restrict__ tk1,
                       unsigned* __restrict__ tk2, double* __restrict__ S1acc,
                       unsigned* __restrict__ flag) {
    int t = threadIdx.x;
    if (blockIdx.x == 0) {
        colsum[t] = 0.f; colsum[t + 256] = 0.f;
        if (t == 0) { *tk1 = 0u; *tk2 = 0u; *S1acc = 0.0; *flag = 0u; }
    }
    int wv = t >> 6, lane = t & 63;
    int row = blockIdx.x * 4 + wv;
    const float4* z4 = (const float4*)zrow(X, Y, row);
    float4 a = z4[lane * 2], b = z4[lane * 2 + 1];
    bf16x8 h;
    h[0] = (bf16_t)a.x; h[1] = (bf16_t)a.y; h[2] = (bf16_t)a.z; h[3] = (bf16_t)a.w;
    h[4] = (bf16_t)b.x; h[5] = (bf16_t)b.y; h[6] = (bf16_t)b.z; h[7] = (bf16_t)b.w;
    *(bf16x8*)(Zh + (size_t)row * DIM + lane * 8) = h;
    float s = a.x*a.x + a.y*a.y + a.z*a.z + a.w*a.w
            + b.x*b.x + b.y*b.y + b.z*b.z + b.w*b.w;
    #pragma unroll
    for (int off = 32; off > 0; off >>= 1) s += __shfl_down(s, off);
    if (lane == 0) sqrow[row] = s;
}

// PERSISTENT fused k_pair: 768 blocks (3/CU, all co-resident).
// All blocks issue tile-0 stages 0/1 first. Blocks 640..767 then run a
// colsum slab at s_setprio(2) (scratch = buffer-2 LDS, untouched by the
// in-flight stages); 128th ticket computes bw -> cvals, zeroes acc, sets
// flag (vmcnt(0)-ordered). Then the R11-verified static 3-tile K-loop:
// 3 stage buffers / 48 KB, one raw s_barrier per K-step, counted
// vmcnt(4), T5 setprio(1) on MFMA, cross-tile stage prefetch at steps
// 14/15 (rotation (g+s)%3), m89/m91 layouts, global-side XOR swizzle.
// Epilogue one-shot-spins on flag (now set @~8us << first epilogue
// @~21us); all blocks co-resident => progress guaranteed. Fence-free
// final ticket -> out.
__global__ __launch_bounds__(256, 3) void k_pair(const bf16_t* __restrict__ Zh,
                                                 const float* __restrict__ sqrow,
                                                 float* __restrict__ colsum,
                                                 float* __restrict__ cvals,
                                                 double* __restrict__ S1acc,
                                                 unsigned* __restrict__ tk1,
                                                 unsigned* __restrict__ flag,
                                                 double* __restrict__ acc,
                                                 unsigned* __restrict__ tk2,
                                                 float* __restrict__ out) {
    int b = blockIdx.x;
    __shared__ bf16_t As[3][4096];   // 3 x 8 KB stage buffers (48 KB total)
    __shared__ bf16_t Bs[3][4096];
    __shared__ float wsum[4];
    __shared__ float lds_c4;

    int t = threadIdx.x, lane = t & 63, wv = t >> 6;
    int n16 = lane & 15, q16 = lane >> 4;

    // static tiles + staging geometry (all blocks)
    int ntile = (b < NTRI - 2 * NPERS) ? 3 : 2;   // b<544: 3 tiles, else 2
    int tis[3], tjs[3];
    #pragma unroll
    for (int g = 0; g < 3; ++g) {
        int T = b + g * NPERS;
        int ti_ = 0, tj_ = 0;
        if (T < NTRI) decode_tile(T, &ti_, &tj_);
        tis[g] = ti_; tjs[g] = tj_;
    }
    int r0_, q0_, r1_, q1_;
    { int c0 = t;       r0_ = c0 >> 2; q0_ = (c0 & 3) ^ ((r0_ >> 1) & 3);
      int c1 = 256 + t; r1_ = c1 >> 2; q1_ = (c1 & 3) ^ ((r1_ >> 1) & 3); }
    int ldsoff0 = (wv * 64) * 8;
    int ldsoff1 = (256 + wv * 64) * 8;
    int wr = wv >> 1, wc = wv & 1;
    int aoff[4], boff[4];
    #pragma unroll
    for (int aa = 0; aa < 4; ++aa) {
        int r = 16 * (wr * 4 + aa) + n16;
        aoff[aa] = (r * 4 + (q16 ^ ((r >> 1) & 3))) * 8;
    }
    #pragma unroll
    for (int bb = 0; bb < 4; ++bb) {
        int r = 16 * (wc * 4 + bb) + n16;
        boff[bb] = (r * 4 + (q16 ^ ((r >> 1) & 3))) * 8;
    }

#define SETPTRS(TI, TJ, A0, B0, A1, B1) do {                        \
        (A0) = Zh + (size_t)((TI) * BT + r0_) * DIM + q0_ * 8;      \
        (B0) = Zh + (size_t)((TJ) * BT + r0_) * DIM + q0_ * 8;      \
        (A1) = Zh + (size_t)((TI) * BT + r1_) * DIM + q1_ * 8;      \
        (B1) = Zh + (size_t)((TJ) * BT + r1_) * DIM + q1_ * 8;      \
    } while (0)
#define STAGEP(A0, B0, A1, B1, KN, BUF) do {                        \
        gload_lds16((A0) + (KN), &As[BUF][ldsoff0]);                \
        gload_lds16((B0) + (KN), &Bs[BUF][ldsoff0]);                \
        gload_lds16((A1) + (KN), &As[BUF][ldsoff1]);                \
        gload_lds16((B1) + (KN), &Bs[BUF][ldsoff1]);                \
    } while (0)
#define WAITBAR(VM) do {                                            \
        asm volatile("s_waitcnt vmcnt(" VM ")" ::: "memory");       \
        __builtin_amdgcn_s_barrier();                               \
        __builtin_amdgcn_sched_barrier(0);                          \
    } while (0)
#define DOMFMA(RB) do {                                             \
        const bf16_t* Ab = &As[RB][0];                              \
        const bf16_t* Bb = &Bs[RB][0];                              \
        bf16x8 av[4], bv[4];                                        \
        _Pragma("unroll")                                           \
        for (int aa = 0; aa < 4; ++aa) av[aa] = *(const bf16x8*)(Ab + aoff[aa]); \
        _Pragma("unroll")                                           \
        for (int bb = 0; bb < 4; ++bb) bv[bb] = *(const bf16x8*)(Bb + boff[bb]); \
        __builtin_amdgcn_s_setprio(1);                              \
        _Pragma("unroll")                                           \
        for (int aa = 0; aa < 4; ++aa)                              \
            _Pragma("unroll")                                       \
            for (int bb = 0; bb < 4; ++bb)                          \
                accf[aa][bb] = __builtin_amdgcn_mfma_f32_16x16x32_bf16( \
                    av[aa], bv[bb], accf[aa][bb], 0, 0, 0);         \
        __builtin_amdgcn_s_setprio(0);                              \
    } while (0)

    // issue tile-0 stages 0/1 FIRST (buffers 0/1; buffer 2 free as scratch)
    const bf16_t *cA0, *cB0, *cA1, *cB1;
    SETPTRS(tis[0], tjs[0], cA0, cB0, cA1, cB1);
    STAGEP(cA0, cB0, cA1, cB1, 0, 0);
    STAGEP(cA0, cB0, cA1, cB1, BK, 1);

    // ---- phase A: colsum + S1 + bw on blocks 640..767, at setprio(2)
    // (above the K-loops' MFMA prio 1 -> no starvation; R13's failure)
    if (b >= CSBASE) {
        __builtin_amdgcn_s_setprio(2);
        double* dred = (double*)&As[2][0];     // 2048 B scratch (buf 2)
        float*  red  = (float*)&Bs[2][0];      // 512 B scratch (buf 2)
        int cb = b - CSBASE;
        int g = cb & 15, slab = cb >> 4;
        int c0 = g * 32 + q16 * 8;
        float s[8] = {0.f,0.f,0.f,0.f,0.f,0.f,0.f,0.f};
        for (int it = 0; it < 16; ++it) {
            int r = slab * 1024 + it * 64 + wv * 16 + n16;
            bf16x8 v = *(const bf16x8*)(Zh + (size_t)r * DIM + c0);
            #pragma unroll
            for (int j = 0; j < 8; ++j) s[j] += (float)v[j];
        }
        #pragma unroll
        for (int off = 8; off >= 1; off >>= 1)
            #pragma unroll
            for (int j = 0; j < 8; ++j) s[j] += __shfl_down(s[j], off);
        if (n16 == 0)
            #pragma unroll
            for (int j = 0; j < 8; ++j) red[(wv * 4 + q16) * 8 + j] = s[j];
        __syncthreads();
        float oldc = 0.f;
        if (t < 32) {
            int q = t >> 3, j = t & 7;
            float v = 0.f;
            #pragma unroll
            for (int w = 0; w < 4; ++w) v += red[(w * 4 + q) * 8 + j];
            oldc = atomicAdd(&colsum[g * 32 + q * 8 + j], v);
        }
        double olds = 0.0;
        if (g == 0) {   // S1 over this slab's 1024 rows
            int i = slab * 1024 + t;
            double d = (double)sqrow[i] + (double)sqrow[i + 256]
                     + (double)sqrow[i + 512] + (double)sqrow[i + 768];
            #pragma unroll
            for (int off = 32; off > 0; off >>= 1) d += __shfl_down(d, off);
            if (lane == 0) olds = atomicAdd(S1acc, d);
        }
        asm volatile("" :: "v"(oldc), "v"(olds));
        asm volatile("s_waitcnt vmcnt(0)" ::: "memory");   // atomics complete
        __syncthreads();
        __shared__ int is_last;
        if (t == 0) is_last = (atomicAdd(tk1, 1u) == 127u);
        __syncthreads();
        if (is_last) {
            float cv0 = atomicAdd(&colsum[t], 0.f);
            float cv1 = atomicAdd(&colsum[t + 256], 0.f);
            dred[t] = (double)cv0 * cv0 + (double)cv1 * cv1;
            __syncthreads();
            for (int off = 128; off > 0; off >>= 1) {
                if (t < off) dred[t] += dred[t + off];
                __syncthreads();
            }
            if (t < 8) {
                unsigned long long o =
                    atomicExch((unsigned long long*)&acc[t * 16], 0ull);
                asm volatile("" :: "v"(o));
            }
            if (t == 0) {
                double S1 = atomicAdd(S1acc, 0.0);
                double n = (double)N_ROWS;
                double bw = (2.0 * n * S1 - 2.0 * dred[0]) / (n * n - n);
                const double LOG2E = 1.4426950408889634;
                double mult = 0.25;
                float olda = 0.f;
                for (int k = 0; k < 5; ++k) {
                    olda += atomicExch(&cvals[k], (float)(-LOG2E / (bw * mult)));
                    mult *= 2.0;
                }
                asm volatile("" :: "v"(olda));
                asm volatile("s_waitcnt vmcnt(0)" ::: "memory");
                unsigned of = atomicExch(flag, 1u);
                asm volatile("" :: "v"(of));
            }
            __syncthreads();
        }
        __builtin_amdgcn_s_setprio(0);
    }

    // ---- phase B: R11-verified static persistent tile loop
    float c4 = 0.f;
    int seen = 0;

    #pragma unroll
    for (int g = 0; g < 3; ++g) {
        if (g >= ntile) break;
        int has_next = (g + 1 < ntile);
        const bf16_t *nA0 = cA0, *nB0 = cB0, *nA1 = cA1, *nB1 = cB1;
        if (has_next) SETPTRS(tis[g + 1], tjs[g + 1], nA0, nB0, nA1, nB1);

        f32x4 accf[4][4];
        #pragma unroll
        for (int a = 0; a < 4; ++a)
            #pragma unroll
            for (int bb = 0; bb < 4; ++bb)
                accf[a][bb] = (f32x4){0.f, 0.f, 0.f, 0.f};

        int rb = g % 3;
        const bf16_t *pA0 = cA0 + 2 * BK, *pB0 = cB0 + 2 * BK;
        const bf16_t *pA1 = cA1 + 2 * BK, *pB1 = cB1 + 2 * BK;
        for (int s = 0; s < 14; ++s) {
            WAITBAR("4");
            int wb = rb + 2; if (wb >= 3) wb -= 3;
            STAGEP(pA0, pB0, pA1, pB1, 0, wb);
            pA0 += BK; pB0 += BK; pA1 += BK; pB1 += BK;
            DOMFMA(rb);
            ++rb; if (rb == 3) rb = 0;
        }
        {   // step 14: read (g+2)%3; stage next tile's stage0 -> (g+1)%3
            WAITBAR("4");
            if (has_next) STAGEP(nA0, nB0, nA1, nB1, 0, (g + 1) % 3);
            DOMFMA((g + 2) % 3);
        }
        {   // step 15: read g%3; stage next tile's stage1 -> (g+2)%3
            if (has_next) {
                WAITBAR("4");
                STAGEP(nA0, nB0, nA1, nB1, BK, (g + 2) % 3);
            } else {
                WAITBAR("0");
            }
            DOMFMA(g % 3);
        }

        // epilogue: one-shot cvals sync, then 5-bandwidth RBF squaring chain
        if (!seen) {
            if (t == 0) {
                while (atomicAdd(flag, 0u) == 0u) __builtin_amdgcn_s_sleep(8);
                lds_c4 = atomicAdd(&cvals[4], 0.f);
            }
            __syncthreads();
            c4 = lds_c4;
            seen = 1;
        }
        int i0 = tis[g] * BT + wr * 64;
        int j0 = tjs[g] * BT + wc * 64;
        float sqi[4][4], sqj[4];
        #pragma unroll
        for (int aa = 0; aa < 4; ++aa)
            #pragma unroll
            for (int r = 0; r < 4; ++r)
                sqi[aa][r] = sqrow[i0 + 16 * aa + q16 * 4 + r];
        #pragma unroll
        for (int bb = 0; bb < 4; ++bb)
            sqj[bb] = sqrow[j0 + 16 * bb + n16];

        float s_local = 0.f;
        #pragma unroll
        for (int aa = 0; aa < 4; ++aa) {
            #pragma unroll
            for (int bb = 0; bb < 4; ++bb) {
                #pragma unroll
                for (int r = 0; r < 4; ++r) {
                    float d2 = fmaf(-2.f, accf[aa][bb][r], sqi[aa][r] + sqj[bb]);
                    d2 = fmaxf(d2, 0.f);
                    float e4 = EXP2F(d2 * c4);
                    float e3 = e4 * e4;
                    float e2 = e3 * e3;
                    float e1 = e2 * e2;
                    float e0 = e1 * e1;
                    s_local += e4 + e3 + e2 + e1 + e0;
                }
            }
        }
        #pragma unroll
        for (int off = 32; off > 0; off >>= 1) s_local += __shfl_down(s_local, off);
        if (lane == 0) wsum[wv] = s_local;
        __syncthreads();   // prefetched next-tile stages long done by now
        if (t == 0) {
            float bs = wsum[0] + wsum[1] + wsum[2] + wsum[3];
            double si = (tis[g] < NT / 2) ? 1.0 : -1.0;
            double sj = (tjs[g] < NT / 2) ? 1.0 : -1.0;
            double w = si * sj * ((tis[g] == tjs[g]) ? 1.0 : 2.0);
            double oldv = atomicAdd(&acc[(b & 7) * 16], w * (double)bs);
            asm volatile("" :: "v"(oldv));
        }
        if (has_next) { cA0 = nA0; cB0 = nB0; cA1 = nA1; cB1 = nB1; }
    }

    // fence-free final ticket (all older VMEM incl. acc atomics retired)
    if (t == 0) {
        asm volatile("s_waitcnt vmcnt(0)" ::: "memory");
        unsigned old = atomicAdd(tk2, 1u);
        if (old == NPERS - 1) {
            double ssum = 0.0;
            #pragma unroll
            for (int i = 0; i < 8; ++i) ssum += atomicAdd(&acc[i * 16], 0.0);
            out[0] = (float)(ssum / ((double)NX * (double)NX));
        }
    }
#undef SETPTRS
#undef STAGEP
#undef WAITBAR
#undef DOMFMA
}

extern "C" void kernel_launch(void* const* d_in, const int* in_sizes, int n_in,
                              void* d_out, int out_size, void* d_ws, size_t ws_size,
                              hipStream_t stream) {
    const float* X = (const float*)d_in[0];
    const float* Y = (const float*)d_in[1];
    float* out = (float*)d_out;

    float*    sqrow  = (float*)d_ws;
    float*    colsum = sqrow + 8192;
    float*    cvals  = (float*)((char*)d_ws + 34816);
    unsigned* tk1    = (unsigned*)((char*)d_ws + 34840);
    unsigned* tk2    = (unsigned*)((char*)d_ws + 34844);
    double*   S1acc  = (double*)((char*)d_ws + 34848);
    unsigned* flag   = (unsigned*)((char*)d_ws + 34860);
    double*   acc    = (double*)((char*)d_ws + 34944);
    bf16_t*   Zh     = (bf16_t*)((char*)d_ws + 36864);

    k_prep<<<2048, 256, 0, stream>>>(X, Y, Zh, sqrow, colsum, tk1, tk2, S1acc, flag);
    k_pair<<<NPERS, 256, 0, stream>>>(Zh, sqrow, colsum, cvals, S1acc, tk1, flag,
                                      acc, tk2, out);
}

// Round 16
// 132.203 us; speedup vs baseline: 1.1220x; 1.1220x over previous
//
#include <hip/hip_runtime.h>

#define N_ROWS 8192
#define NX     4096
#define DIM    512
#define BT     128          // block tile (rows & cols)
#define NT     64           // N_ROWS / BT tiles per side
#define NTRI   2080         // NT*(NT+1)/2 upper-triangle tiles
#define BK     32           // K elements per stage (64 B per row)
#define NMAIN  2048         // k_prep main blocks (Zh + sqrow)
#define NCS    128          // k_prep colsum blocks (read X/Y directly)

typedef __bf16 bf16_t;
typedef bf16_t bf16x8 __attribute__((ext_vector_type(8)));
typedef float  f32x4  __attribute__((ext_vector_type(4)));

#if __has_builtin(__builtin_amdgcn_exp2f)
  #define EXP2F __builtin_amdgcn_exp2f
#else
  #define EXP2F exp2f
#endif

// ws layout (bytes) — identical footprint to all prior rounds:
//   0       sqrow[8192]  float
//   32768   colsum[512]  float
//   34816   cvals[5]     float   cvals[k] = -log2e/(bw*mult_k)
//   34840   tk1          uint    colsum ticket (within k_prep)
//   34844   tk2          uint    final ticket (within k_pair)
//   34848   S1acc        double  sum of z^2 (fp64)
//   34944   acc[8*16]    double  8 slots, 128 B apart
//   36864   Zh[8192*512] bf16
//
// Structure: k_zero (1 blk: zero colsum/tk1/S1acc) -> k_prep (2048 main
// blocks: Zh+sqrow, block 0 zeroes acc/tk2; +128 colsum blocks reading
// X/Y DIRECTLY -> colsum/S1 atomics -> 128th ticket computes bw->cvals
// with plain stores) -> k_pair (R10 VERBATIM, no flag/spin: cvals is
// ready at launch boundary). R12-R14 lesson: in-kernel producer->consumer
// (flag spin) costs ~35-40 us via an unidentified global serialization;
// colsum-from-inputs removes the dependency instead of managing it.
// NO __threadfence anywhere (R7/R8: per-block L2 writeback doubled stage
// latency chip-wide). Ordering = returning atomic -> asm sink ->
// s_waitcnt vmcnt(0) -> ticket atomic.

__device__ __forceinline__ const float* zrow(const float* X, const float* Y, int r) {
    return (r < NX) ? (X + (size_t)r * DIM) : (Y + (size_t)(r - NX) * DIM);
}

// async 16B global -> LDS (lane-contiguous dest: ldsbase + lane*16)
__device__ __forceinline__ void gload_lds16(const bf16_t* g, bf16_t* l) {
    __builtin_amdgcn_global_load_lds(
        (__attribute__((address_space(1))) void*)(void*)(g),
        (__attribute__((address_space(3))) void*)(void*)(l), 16, 0, 0);
}

__global__ void k_zero(float* __restrict__ colsum, unsigned* __restrict__ tk1,
                       double* __restrict__ S1acc) {
    int t = threadIdx.x;
    colsum[t] = 0.f; colsum[t + 256] = 0.f;
    if (t == 0) { *tk1 = 0u; *S1acc = 0.0; }
}

// k_prep: blocks 0..2047 = bf16 copy + exact fp32 row norms (block 0 also
// zeroes acc/tk2 — consumed only by the NEXT launch, no intra-launch race).
// Blocks 2048..2175 = colsum + S1 read DIRECTLY from X/Y (16 groups x 8
// slabs; slab s<4 entirely in X, s>=4 in Y), then ticketed bw -> cvals.
__global__ void k_prep(const float* __restrict__ X, const float* __restrict__ Y,
                       bf16_t* __restrict__ Zh, float* __restrict__ sqrow,
                       float* __restrict__ colsum, float* __restrict__ cvals,
                       unsigned* __restrict__ tk1, unsigned* __restrict__ tk2,
                       double* __restrict__ S1acc, double* __restrict__ acc) {
    __shared__ float  redc[32][8][4];   // colsum cross-rowgroup reduce (4 KB)
    __shared__ double redd[4];          // ssq per-wave partials
    __shared__ double dred2[256];       // CS reduce in last block
    __shared__ int    is_last;
    int bid = blockIdx.x;
    int t = threadIdx.x, lane = t & 63, wv = t >> 6;

    if (bid < NMAIN) {
        if (bid == 0) {
            if (t < 8) acc[t * 16] = 0.0;
            if (t == 0) *tk2 = 0u;      // plain stores: next-launch consumers
        }
        int row = bid * 4 + wv;
        const float4* z4 = (const float4*)zrow(X, Y, row);
        float4 a = z4[lane * 2], b = z4[lane * 2 + 1];
        bf16x8 h;
        h[0] = (bf16_t)a.x; h[1] = (bf16_t)a.y; h[2] = (bf16_t)a.z; h[3] = (bf16_t)a.w;
        h[4] = (bf16_t)b.x; h[5] = (bf16_t)b.y; h[6] = (bf16_t)b.z; h[7] = (bf16_t)b.w;
        *(bf16x8*)(Zh + (size_t)row * DIM + lane * 8) = h;
        float s = a.x*a.x + a.y*a.y + a.z*a.z + a.w*a.w
                + b.x*b.x + b.y*b.y + b.z*b.z + b.w*b.w;
        #pragma unroll
        for (int off = 32; off > 0; off >>= 1) s += __shfl_down(s, off);
        if (lane == 0) sqrow[row] = s;
        return;
    }

    // ---- colsum duty: cb in 0..127; group g (32 cols), slab (1024 rows)
    int cb = bid - NMAIN;
    int g = cb & 15, slab = cb >> 4;
    const float* base = (slab < 4) ? (X + (size_t)slab * 1024 * DIM)
                                   : (Y + (size_t)(slab - 4) * 1024 * DIM);
    int c4off = g * 32 + (t & 7) * 4;   // float4 column offset
    int rl0 = t >> 3;                   // row-in-group 0..31
    float cs0 = 0.f, cs1 = 0.f, cs2 = 0.f, cs3 = 0.f;
    double ssq = 0.0;
    for (int it = 0; it < 32; ++it) {
        float4 v = *(const float4*)(base + (size_t)(it * 32 + rl0) * DIM + c4off);
        cs0 += v.x; cs1 += v.y; cs2 += v.z; cs3 += v.w;
        ssq += (double)v.x * v.x + (double)v.y * v.y
             + (double)v.z * v.z + (double)v.w * v.w;
    }
    redc[rl0][t & 7][0] = cs0; redc[rl0][t & 7][1] = cs1;
    redc[rl0][t & 7][2] = cs2; redc[rl0][t & 7][3] = cs3;
    #pragma unroll
    for (int off = 32; off > 0; off >>= 1) ssq += __shfl_down(ssq, off);
    if (lane == 0) redd[wv] = ssq;
    __syncthreads();
    float oldc = 0.f; double olds = 0.0;
    if (t < 32) {                        // col c = t within the group
        float v = 0.f;
        #pragma unroll
        for (int r = 0; r < 32; ++r) v += redc[r][t >> 2][t & 3];
        oldc = atomicAdd(&colsum[g * 32 + t], v);       // returning form
    }
    if (t == 0)
        olds = atomicAdd(S1acc, redd[0] + redd[1] + redd[2] + redd[3]);
    asm volatile("" :: "v"(oldc), "v"(olds));           // keep returns live
    asm volatile("s_waitcnt vmcnt(0)" ::: "memory");    // atomics completed
    __syncthreads();
    if (t == 0) is_last = (atomicAdd(tk1, 1u) == NCS - 1u);
    __syncthreads();
    if (!is_last) return;
    // last colsum block: CS = ||colsum||^2, bw, cvals (plain stores —
    // kernel boundary publishes them to k_pair)
    float cv0 = atomicAdd(&colsum[t], 0.f);             // atomic read
    float cv1 = atomicAdd(&colsum[t + 256], 0.f);
    dred2[t] = (double)cv0 * cv0 + (double)cv1 * cv1;
    __syncthreads();
    for (int off = 128; off > 0; off >>= 1) {
        if (t < off) dred2[t] += dred2[t + off];
        __syncthreads();
    }
    if (t == 0) {
        double S1 = atomicAdd(S1acc, 0.0);              // atomic read
        double n = (double)N_ROWS;
        double bw = (2.0 * n * S1 - 2.0 * dred2[0]) / (n * n - n);
        const double LOG2E = 1.4426950408889634;
        double mult = 0.25;
        for (int k = 0; k < 5; ++k) {
            cvals[k] = (float)(-LOG2E / (bw * mult));
            mult *= 2.0;
        }
    }
}

// ===== k_pair: R10 VERBATIM (measured 63.4 us, absmax 0.0) =====
// 128x128 tile over upper triangle; 3 stage buffers (48 KB -> 3 blocks/CU),
// one raw s_barrier per K-step, counted vmcnt(4) (never 0 in main loop),
// T5 setprio, SUPERTILE-blocked enumeration (XCD-local L2 working set),
// epilogue sqrow/cvals prefetched before STAGE(0), m89/m91-verified
// layouts, global-side XOR swizzle, fence-free ticketed final reduce.
__global__ __launch_bounds__(256, 3) void k_pair(const bf16_t* __restrict__ Zh,
                                                 const float* __restrict__ sqrow,
                                                 const float* __restrict__ cvals,
                                                 double* __restrict__ acc,
                                                 unsigned* __restrict__ tk2,
                                                 float* __restrict__ out) {
    // XCD-chunked swizzle (bijective: 2080 = 8 * 260)
    int L0 = blockIdx.x;
    int q = (L0 & 7) * (NTRI / 8) + (L0 >> 3);
    // supertile decode: row I of supertiles has 36 + (7-I)*64 tiles
    int ti, tj;
    {
        int I = 0, rem = q;
        #pragma unroll
        for (int it = 0; it < 8; ++it) {
            int rowcnt = 36 + (7 - I) * 64;
            if (rem >= rowcnt && I < 7) { rem -= rowcnt; ++I; } else break;
        }
        if (rem < 36) {            // diagonal supertile (I,I): pairs a<=b
            int a = 0;
            #pragma unroll
            for (int it = 0; it < 7; ++it) {
                int nxt = (a + 1) * 8 - (a + 1) * a / 2;
                if (nxt <= rem) ++a; else break;
            }
            int off = a * 8 - a * (a - 1) / 2;
            ti = I * 8 + a;
            tj = I * 8 + a + (rem - off);
        } else {                   // off-diagonal supertile (I,J), J>I
            int r2 = rem - 36;
            int J = I + 1 + (r2 >> 6);
            int w = r2 & 63;
            ti = I * 8 + (w >> 3);
            tj = J * 8 + (w & 7);
        }
    }

    __shared__ bf16_t As[3][4096];   // 3 x 8 KB stage buffers
    __shared__ bf16_t Bs[3][4096];   // total 48 KB -> 3 blocks/CU
    __shared__ float wsum[4];

    int t = threadIdx.x, lane = t & 63, wv = t >> 6;
    int wr = wv >> 1, wc = wv & 1;
    int i0 = ti * BT + wr * 64;
    int j0 = tj * BT + wc * 64;

    // staging addressing: issue h covers chunks h*256+t; chunk c: row r=c>>2,
    // phys slot sq=c&3 holds logical chunk q = sq ^ ((r>>1)&3)
    const bf16_t* gA[2]; const bf16_t* gB[2];
    {
        int c0 = t, r0 = c0 >> 2, sq0 = c0 & 3, q0 = sq0 ^ ((r0 >> 1) & 3);
        int c1 = 256 + t, r1 = c1 >> 2, sq1 = c1 & 3, q1 = sq1 ^ ((r1 >> 1) & 3);
        gA[0] = Zh + (size_t)(ti * BT + r0) * DIM + q0 * 8;
        gB[0] = Zh + (size_t)(tj * BT + r0) * DIM + q0 * 8;
        gA[1] = Zh + (size_t)(ti * BT + r1) * DIM + q1 * 8;
        gB[1] = Zh + (size_t)(tj * BT + r1) * DIM + q1 * 8;
    }
    int ldsoff0 = (wv * 64) * 8;            // wave-uniform; lane*16B implicit
    int ldsoff1 = (256 + wv * 64) * 8;

    // fragment LDS element offsets (row r, logical k-chunk q16 -> phys slot)
    int n16 = lane & 15, q16 = lane >> 4;
    int aoff[4], boff[4];
    #pragma unroll
    for (int aa = 0; aa < 4; ++aa) {
        int r = 16 * (wr * 4 + aa) + n16;
        aoff[aa] = (r * 4 + (q16 ^ ((r >> 1) & 3))) * 8;
    }
    #pragma unroll
    for (int bb = 0; bb < 4; ++bb) {
        int r = 16 * (wc * 4 + bb) + n16;
        boff[bb] = (r * 4 + (q16 ^ ((r >> 1) & 3))) * 8;
    }

    // epilogue-data prefetch: issued BEFORE stage 0, so the loop's first
    // vmcnt(4) (stage0 done, stage1 in flight) also retires these.
    float c4 = cvals[4];
    float sqi[4][4], sqj[4];
    #pragma unroll
    for (int aa = 0; aa < 4; ++aa)
        #pragma unroll
        for (int r = 0; r < 4; ++r)
            sqi[aa][r] = sqrow[i0 + 16 * aa + q16 * 4 + r];
    #pragma unroll
    for (int bb = 0; bb < 4; ++bb)
        sqj[bb] = sqrow[j0 + 16 * bb + n16];

    f32x4 accf[4][4];
    #pragma unroll
    for (int a = 0; a < 4; ++a)
        #pragma unroll
        for (int b = 0; b < 4; ++b)
            accf[a][b] = (f32x4){0.f, 0.f, 0.f, 0.f};

#define STAGE(S) do {                                   \
        int _b = (S) % 3; int _kn = (S) * BK;           \
        gload_lds16(gA[0] + _kn, &As[_b][ldsoff0]);     \
        gload_lds16(gB[0] + _kn, &Bs[_b][ldsoff0]);     \
        gload_lds16(gA[1] + _kn, &As[_b][ldsoff1]);     \
        gload_lds16(gB[1] + _kn, &Bs[_b][ldsoff1]);     \
    } while (0)

#define KSTEP(S, VM, DO_STAGE) do {                                          \
        asm volatile("s_waitcnt vmcnt(" VM ")" ::: "memory");                \
        __builtin_amdgcn_s_barrier();                                        \
        __builtin_amdgcn_sched_barrier(0);                                   \
        if (DO_STAGE) STAGE((S) + 2);                                        \
        const bf16_t* Ab = &As[(S) % 3][0];                                  \
        const bf16_t* Bb = &Bs[(S) % 3][0];                                  \
        bf16x8 a[4], b[4];                                                   \
        _Pragma("unroll")                                                    \
        for (int aa = 0; aa < 4; ++aa) a[aa] = *(const bf16x8*)(Ab + aoff[aa]); \
        _Pragma("unroll")                                                    \
        for (int bb = 0; bb < 4; ++bb) b[bb] = *(const bf16x8*)(Bb + boff[bb]); \
        __builtin_amdgcn_s_setprio(1);                                       \
        _Pragma("unroll")                                                    \
        for (int aa = 0; aa < 4; ++aa)                                       \
            _Pragma("unroll")                                                \
            for (int bb = 0; bb < 4; ++bb)                                   \
                accf[aa][bb] = __builtin_amdgcn_mfma_f32_16x16x32_bf16(      \
                    a[aa], b[bb], accf[aa][bb], 0, 0, 0);                    \
        __builtin_amdgcn_s_setprio(0);                                       \
    } while (0)

    // prologue: stages 0,1 in flight (8 vmem/thread, after prefetch loads)
    STAGE(0); STAGE(1);
    // steady state: wait vmcnt(4) = stage s drained, s+1 outstanding
    KSTEP( 0, "4", 1); KSTEP( 1, "4", 1); KSTEP( 2, "4", 1); KSTEP( 3, "4", 1);
    KSTEP( 4, "4", 1); KSTEP( 5, "4", 1); KSTEP( 6, "4", 1); KSTEP( 7, "4", 1);
    KSTEP( 8, "4", 1); KSTEP( 9, "4", 1); KSTEP(10, "4", 1); KSTEP(11, "4", 1);
    KSTEP(12, "4", 1); KSTEP(13, "4", 1);    // stage 15 issued here
    KSTEP(14, "4", 0);                       // outstanding: 15 = 4
    KSTEP(15, "0", 0);                       // drain
#undef KSTEP
#undef STAGE

    // epilogue: D2 -> 5-bandwidth RBF via squaring chain:
    // c_k halves per k => e_k = e4^(2^(4-k)); 1 exp + 4 muls per d2
    float s_local = 0.f;
    #pragma unroll
    for (int aa = 0; aa < 4; ++aa) {
        #pragma unroll
        for (int bb = 0; bb < 4; ++bb) {
            #pragma unroll
            for (int r = 0; r < 4; ++r) {
                float d2 = fmaf(-2.f, accf[aa][bb][r], sqi[aa][r] + sqj[bb]);
                d2 = fmaxf(d2, 0.f);
                float e4 = EXP2F(d2 * c4);       // smallest |c|
                float e3 = e4 * e4;
                float e2 = e3 * e3;
                float e1 = e2 * e2;
                float e0 = e1 * e1;
                s_local += e4 + e3 + e2 + e1 + e0;
            }
        }
    }
    #pragma unroll
    for (int off = 32; off > 0; off >>= 1) s_local += __shfl_down(s_local, off);
    if (lane == 0) wsum[wv] = s_local;
    __syncthreads();
    if (t == 0) {
        float bs = wsum[0] + wsum[1] + wsum[2] + wsum[3];
        double si = (ti < NT / 2) ? 1.0 : -1.0;
        double sj = (tj < NT / 2) ? 1.0 : -1.0;
        double w = si * sj * ((ti == tj) ? 1.0 : 2.0);
        // fence-free ordered ticket: returning atomic -> vmcnt(0) -> ticket
        double oldv = atomicAdd(&acc[(L0 & 7) * 16], w * (double)bs);
        asm volatile("" :: "v"(oldv));
        asm volatile("s_waitcnt vmcnt(0)" ::: "memory");
        unsigned old = atomicAdd(tk2, 1u);
        if (old == NTRI - 1) {               // last block: final reduce -> out
            double ssum = 0.0;
            #pragma unroll
            for (int i = 0; i < 8; ++i) ssum += atomicAdd(&acc[i * 16], 0.0);
            out[0] = (float)(ssum / ((double)NX * (double)NX));
        }
    }
}

extern "C" void kernel_launch(void* const* d_in, const int* in_sizes, int n_in,
                              void* d_out, int out_size, void* d_ws, size_t ws_size,
                              hipStream_t stream) {
    const float* X = (const float*)d_in[0];
    const float* Y = (const float*)d_in[1];
    float* out = (float*)d_out;

    float*    sqrow  = (float*)d_ws;
    float*    colsum = sqrow + 8192;
    float*    cvals  = (float*)((char*)d_ws + 34816);
    unsigned* tk1    = (unsigned*)((char*)d_ws + 34840);
    unsigned* tk2    = (unsigned*)((char*)d_ws + 34844);
    double*   S1acc  = (double*)((char*)d_ws + 34848);
    double*   acc    = (double*)((char*)d_ws + 34944);
    bf16_t*   Zh     = (bf16_t*)((char*)d_ws + 36864);

    k_zero<<<1, 256, 0, stream>>>(colsum, tk1, S1acc);
    k_prep<<<NMAIN + NCS, 256, 0, stream>>>(X, Y, Zh, sqrow, colsum, cvals,
                                            tk1, tk2, S1acc, acc);
    k_pair<<<NTRI, 256, 0, stream>>>(Zh, sqrow, cvals, acc, tk2, out);
}